// Round 1
// baseline (29.895 us; speedup 1.0000x reference)
//
#include <hip/hip_runtime.h>

// Problem constants (from setup_inputs: B=8, H=64, W=64)
#define BATCH 8
#define N 4096          // H*W
#define TPB 256
#define SPLITS 32       // blocks per sample in kernel 2; each covers 128 i-values

// ---------------------------------------------------------------------------
// Kernel 1: per-sample max + pos/neg counts -> ws[b*2] = 1/max,
// ws[b*2+1] = valid ? 1/((npos*nneg+1e-8)*B) : 0.  Also zeroes d_out.
// ---------------------------------------------------------------------------
__global__ void srs_prep_kernel(const float* __restrict__ pred,
                                const float* __restrict__ mask,
                                float* __restrict__ wsf,
                                float* __restrict__ out) {
    int b = blockIdx.x;
    int tid = threadIdx.x;
    const float* xb = pred + b * N;
    const float* mb = mask + b * N;

    float lmax = -3.4e38f;
    int lpos = 0, lneg = 0;
    for (int j = tid; j < N; j += TPB) {
        float v = xb[j];
        lmax = fmaxf(lmax, v);
        float m = mb[j];
        lpos += (m > 0.5f) ? 1 : 0;
        lneg += (m < 0.5f) ? 1 : 0;
    }
    // wave (64-lane) reduction
    for (int off = 32; off > 0; off >>= 1) {
        lmax = fmaxf(lmax, __shfl_down(lmax, off));
        lpos += __shfl_down(lpos, off);
        lneg += __shfl_down(lneg, off);
    }
    __shared__ float smax[4];
    __shared__ int spos[4], sneg[4];
    int wid = tid >> 6;
    if ((tid & 63) == 0) { smax[wid] = lmax; spos[wid] = lpos; sneg[wid] = lneg; }
    __syncthreads();
    if (tid == 0) {
        float mx = fmaxf(fmaxf(smax[0], smax[1]), fmaxf(smax[2], smax[3]));
        int np = spos[0] + spos[1] + spos[2] + spos[3];
        int nn = sneg[0] + sneg[1] + sneg[2] + sneg[3];
        float denom = (float)np * (float)nn + 1e-8f;
        float scale = (np > 0 && nn > 0) ? 1.0f / (denom * (float)BATCH) : 0.0f;
        wsf[b * 2 + 0] = 1.0f / mx;
        wsf[b * 2 + 1] = scale;
        if (b == 0) out[0] = 0.0f;   // kernel order on stream guarantees this lands first
    }
}

// ---------------------------------------------------------------------------
// Kernel 2: pairwise accumulation.
// grid = BATCH * SPLITS blocks, 256 threads.
//   block -> sample b = blockIdx/SPLITS, i-chunk = blockIdx%SPLITS (128 i's).
//   LDS holds xjb[j] = (neg j) ? x_j + 0.5 : -1e30   (auto-zero via relu)
//   thread: i = chunk*128 + (tid&127); j-half = tid>>7 (2048 j's each)
//   xi = (pos i) ? x_i : +1e30                        (auto-zero via relu)
// ---------------------------------------------------------------------------
__global__ void srs_pairs_kernel(const float* __restrict__ pred,
                                 const float* __restrict__ mask,
                                 const float* __restrict__ wsf,
                                 float* __restrict__ out) {
    int b = blockIdx.x >> 5;        // / SPLITS
    int chunk = blockIdx.x & 31;    // % SPLITS
    int tid = threadIdx.x;
    const float* xb = pred + b * N;
    const float* mb = mask + b * N;
    float rmax  = wsf[b * 2 + 0];
    float scale = wsf[b * 2 + 1];

    __shared__ float4 xjb4[N / 4];
    float* xjb = (float*)xjb4;
    for (int j = tid; j < N; j += TPB) {
        float xv = xb[j] * rmax;
        xjb[j] = (mb[j] < 0.5f) ? (xv + 0.5f) : -1.0e30f;
    }
    __syncthreads();

    int ii = tid & 127;
    int i = chunk * 128 + ii;
    int jhalf = tid >> 7;           // 0 or 1
    float xi = (mb[i] > 0.5f) ? (xb[i] * rmax) : 1.0e30f;

    float a0 = 0.f, a1 = 0.f, a2 = 0.f, a3 = 0.f;
    int j4beg = jhalf * (N / 8);    // float4 units; N/4 total, half each
    int j4end = j4beg + (N / 8);
#pragma unroll 4
    for (int j4 = j4beg; j4 < j4end; ++j4) {
        float4 v = xjb4[j4];        // wave-uniform address -> LDS broadcast
        a0 += fmaxf(v.x - xi, 0.0f);
        a1 += fmaxf(v.y - xi, 0.0f);
        a2 += fmaxf(v.z - xi, 0.0f);
        a3 += fmaxf(v.w - xi, 0.0f);
    }
    float acc = (a0 + a1) + (a2 + a3);

    // block reduction: 64-lane shuffle, then cross-wave via LDS
    for (int off = 32; off > 0; off >>= 1) acc += __shfl_down(acc, off);
    __shared__ float wsum[4];
    if ((tid & 63) == 0) wsum[tid >> 6] = acc;
    __syncthreads();
    if (tid == 0) {
        float total = (wsum[0] + wsum[1]) + (wsum[2] + wsum[3]);
        atomicAdd(out, total * scale);
    }
}

extern "C" void kernel_launch(void* const* d_in, const int* in_sizes, int n_in,
                              void* d_out, int out_size, void* d_ws, size_t ws_size,
                              hipStream_t stream) {
    const float* pred = (const float*)d_in[0];
    const float* mask = (const float*)d_in[1];
    float* out = (float*)d_out;
    float* wsf = (float*)d_ws;

    srs_prep_kernel<<<BATCH, TPB, 0, stream>>>(pred, mask, wsf, out);
    srs_pairs_kernel<<<BATCH * SPLITS, TPB, 0, stream>>>(pred, mask, wsf, out);
}

// Round 2
// 21.720 us; speedup vs baseline: 1.3764x; 1.3764x over previous
//
#include <hip/hip_runtime.h>

// Problem constants: B=8, H=64, W=64 -> N=4096 per sample
#define BATCH 8
#define N 4096
#define TPB 512
#define SPB 32                  // blocks per sample
#define NBLK (BATCH * SPB)      // 256 blocks = 1 per CU, 8 waves/CU
#define COMB_SZ 4104            // neg (front, padded to x4) + pos (back); npos+nneg<=4096

// Single fused kernel:
//   pass 1: per-sample max (block-redundant, cheap)
//   pass 2: ballot-compact  neg -> comb[0..nneg)  as x/max + 0.5
//                           pos -> comb[back]     as x/max
//   pass 3: pair loop over compacted lists only (~25% of naive pairs)
//           relu(0.5 - (xi - xj)) == relu(combneg[j] - xi)
__global__ __launch_bounds__(TPB) void srs_fused_kernel(
    const float* __restrict__ pred,
    const float* __restrict__ mask,
    float* __restrict__ out)
{
    int b   = blockIdx.x >> 5;   // / SPB
    int c   = blockIdx.x & 31;   // % SPB
    int tid = threadIdx.x;
    int lane = tid & 63;
    int wid  = tid >> 6;         // 0..7
    const float* xb = pred + b * N;
    const float* mb = mask + b * N;

    __shared__ float4 comb4[COMB_SZ / 4];   // 4104 floats, 16416 B
    float* comb = (float*)comb4;
    __shared__ float red[8];
    __shared__ int   ctr[2];                // [0]=npos, [1]=nneg
    __shared__ float srmax;

    // ---- pass 1: sample max ----
    const float4* xb4 = (const float4*)xb;
    const float4* mb4 = (const float4*)mb;
    float lmax = -3.4e38f;
#pragma unroll
    for (int e = 0; e < N / 4 / TPB; ++e) {         // 2 iters
        float4 v = xb4[tid + e * TPB];
        lmax = fmaxf(fmaxf(lmax, fmaxf(v.x, v.y)), fmaxf(v.z, v.w));
    }
    for (int off = 32; off > 0; off >>= 1)
        lmax = fmaxf(lmax, __shfl_down(lmax, off));
    if (lane == 0) red[wid] = lmax;
    if (tid == 0) { ctr[0] = 0; ctr[1] = 0; }
    __syncthreads();
    if (tid == 0) {
        float mx = red[0];
#pragma unroll
        for (int w = 1; w < 8; ++w) mx = fmaxf(mx, red[w]);
        srmax = 1.0f / mx;
    }
    __syncthreads();
    float rmax = srmax;

    // ---- pass 2: classify + wave-ballot compaction (order-free) ----
#pragma unroll
    for (int e = 0; e < N / 4 / TPB; ++e) {
        float4 xv = xb4[tid + e * TPB];
        float4 mv = mb4[tid + e * TPB];
        float xs[4] = {xv.x, xv.y, xv.z, xv.w};
        float ms[4] = {mv.x, mv.y, mv.z, mv.w};
#pragma unroll
        for (int q = 0; q < 4; ++q) {
            float nv = xs[q] * rmax;
            bool isp = ms[q] > 0.5f;
            bool isn = ms[q] < 0.5f;
            unsigned long long bp = __ballot(isp);
            unsigned long long bn = __ballot(isn);
            int basep = 0, basen = 0;
            if (lane == 0) {
                basep = atomicAdd(&ctr[0], __popcll(bp));
                basen = atomicAdd(&ctr[1], __popcll(bn));
            }
            basep = __shfl(basep, 0);
            basen = __shfl(basen, 0);
            unsigned long long lower = (1ull << lane) - 1ull;
            if (isp) comb[COMB_SZ - 1 - (basep + __popcll(bp & lower))] = nv;
            if (isn) comb[basen + __popcll(bn & lower)] = nv + 0.5f;
        }
    }
    __syncthreads();
    int npos = ctr[0], nneg = ctr[1];
    int nneg4 = (nneg + 3) & ~3;
    if (tid < nneg4 - nneg) comb[nneg + tid] = -1.0e30f;  // pad: contributes 0
    __syncthreads();

    // ---- pass 3: pair loop over compacted lists ----
    // wave = 64 lanes, all same jsplit -> comb4[j4] is a full-wave broadcast
    int ii = tid & 63;
    int jsplit = tid >> 6;       // 0..7
    int nj4 = nneg4 >> 2;
    float a0 = 0.f, a1 = 0.f, a2 = 0.f, a3 = 0.f;
    for (int ip = c * 64 + ii; ip < npos; ip += SPB * 64) {
        float xi = comb[COMB_SZ - 1 - ip];
        for (int j4 = jsplit; j4 < nj4; j4 += 8) {
            float4 v = comb4[j4];
            a0 += fmaxf(v.x - xi, 0.f);
            a1 += fmaxf(v.y - xi, 0.f);
            a2 += fmaxf(v.z - xi, 0.f);
            a3 += fmaxf(v.w - xi, 0.f);
        }
    }
    float acc = (a0 + a1) + (a2 + a3);
    for (int off = 32; off > 0; off >>= 1) acc += __shfl_down(acc, off);
    __syncthreads();             // red[] reuse
    if (lane == 0) red[wid] = acc;
    __syncthreads();
    if (tid == 0) {
        float tot = 0.f;
#pragma unroll
        for (int w = 0; w < 8; ++w) tot += red[w];
        float denom = (float)npos * (float)nneg + 1e-8f;
        float scale = (npos > 0 && nneg > 0) ? 1.0f / (denom * (float)BATCH) : 0.0f;
        atomicAdd(out, tot * scale);
    }
}

extern "C" void kernel_launch(void* const* d_in, const int* in_sizes, int n_in,
                              void* d_out, int out_size, void* d_ws, size_t ws_size,
                              hipStream_t stream) {
    const float* pred = (const float*)d_in[0];
    const float* mask = (const float*)d_in[1];
    float* out = (float*)d_out;

    hipMemsetAsync(out, 0, sizeof(float) * out_size, stream);
    srs_fused_kernel<<<NBLK, TPB, 0, stream>>>(pred, mask, out);
}

// Round 3
// 18.696 us; speedup vs baseline: 1.5990x; 1.1617x over previous
//
#include <hip/hip_runtime.h>

// Problem constants: B=8, H=64, W=64 -> N=4096 per sample
#define BATCH 8
#define N 4096
#define TPB 512
#define SPB 32                  // blocks per sample
#define NBLK (BATCH * SPB)      // 256 blocks (power of 2 -> counter mod works)
#define COMB_SZ 4104            // neg (front, padded to x4) + pos (back)

// Single fused kernel, single graph node:
//   pass 1: per-sample max (block-redundant, cheap)
//   pass 2: ballot-compact  neg -> comb[0..nneg)  as x/max + 0.5
//                           pos -> comb[back]     as x/max
//   pass 3: pair loop over compacted lists (~25% of naive pairs)
//   finish: partial -> d_ws (agent-scope release), counter mod-256 elects the
//           last block, which reduces 256 partials and plain-stores out[0].
//           Counter needs NO init: any start value works mod 256.
__global__ __launch_bounds__(TPB) void srs_fused_kernel(
    const float* __restrict__ pred,
    const float* __restrict__ mask,
    float* __restrict__ out,
    float* __restrict__ partials,       // [NBLK] in d_ws
    unsigned int* __restrict__ cnt)     // 1 uint in d_ws (never re-initialized)
{
    int b   = blockIdx.x >> 5;   // / SPB
    int c   = blockIdx.x & 31;   // % SPB
    int tid = threadIdx.x;
    int lane = tid & 63;
    int wid  = tid >> 6;         // 0..7
    const float* xb = pred + b * N;
    const float* mb = mask + b * N;

    __shared__ float4 comb4[COMB_SZ / 4];   // 16416 B
    float* comb = (float*)comb4;
    __shared__ float red[8];
    __shared__ int   ctr[2];                // [0]=npos, [1]=nneg
    __shared__ float srmax;
    __shared__ int   sLast;

    // ---- pass 1: sample max ----
    const float4* xb4 = (const float4*)xb;
    const float4* mb4 = (const float4*)mb;
    float lmax = -3.4e38f;
#pragma unroll
    for (int e = 0; e < N / 4 / TPB; ++e) {         // 2 iters
        float4 v = xb4[tid + e * TPB];
        lmax = fmaxf(fmaxf(lmax, fmaxf(v.x, v.y)), fmaxf(v.z, v.w));
    }
    for (int off = 32; off > 0; off >>= 1)
        lmax = fmaxf(lmax, __shfl_down(lmax, off));
    if (lane == 0) red[wid] = lmax;
    if (tid == 0) { ctr[0] = 0; ctr[1] = 0; }
    __syncthreads();
    if (tid == 0) {
        float mx = red[0];
#pragma unroll
        for (int w = 1; w < 8; ++w) mx = fmaxf(mx, red[w]);
        srmax = 1.0f / mx;
    }
    __syncthreads();
    float rmax = srmax;

    // ---- pass 2: classify + wave-ballot compaction (order-free) ----
#pragma unroll
    for (int e = 0; e < N / 4 / TPB; ++e) {
        float4 xv = xb4[tid + e * TPB];
        float4 mv = mb4[tid + e * TPB];
        float xs[4] = {xv.x, xv.y, xv.z, xv.w};
        float ms[4] = {mv.x, mv.y, mv.z, mv.w};
#pragma unroll
        for (int q = 0; q < 4; ++q) {
            float nv = xs[q] * rmax;
            bool isp = ms[q] > 0.5f;
            bool isn = ms[q] < 0.5f;
            unsigned long long bp = __ballot(isp);
            unsigned long long bn = __ballot(isn);
            int basep = 0, basen = 0;
            if (lane == 0) {
                basep = atomicAdd(&ctr[0], __popcll(bp));
                basen = atomicAdd(&ctr[1], __popcll(bn));
            }
            basep = __shfl(basep, 0);
            basen = __shfl(basen, 0);
            unsigned long long lower = (1ull << lane) - 1ull;
            if (isp) comb[COMB_SZ - 1 - (basep + __popcll(bp & lower))] = nv;
            if (isn) comb[basen + __popcll(bn & lower)] = nv + 0.5f;
        }
    }
    __syncthreads();
    int npos = ctr[0], nneg = ctr[1];
    int nneg4 = (nneg + 3) & ~3;
    if (tid < nneg4 - nneg) comb[nneg + tid] = -1.0e30f;  // pad contributes 0
    __syncthreads();

    // ---- pass 3: pair loop over compacted lists ----
    int ii = tid & 63;
    int jsplit = tid >> 6;       // 0..7
    int nj4 = nneg4 >> 2;
    float a0 = 0.f, a1 = 0.f, a2 = 0.f, a3 = 0.f;
    for (int ip = c * 64 + ii; ip < npos; ip += SPB * 64) {
        float xi = comb[COMB_SZ - 1 - ip];
#pragma unroll 4
        for (int j4 = jsplit; j4 < nj4; j4 += 8) {
            float4 v = comb4[j4];    // wave-uniform address -> LDS broadcast
            a0 += fmaxf(v.x - xi, 0.f);
            a1 += fmaxf(v.y - xi, 0.f);
            a2 += fmaxf(v.z - xi, 0.f);
            a3 += fmaxf(v.w - xi, 0.f);
        }
    }
    float acc = (a0 + a1) + (a2 + a3);
    for (int off = 32; off > 0; off >>= 1) acc += __shfl_down(acc, off);
    __syncthreads();             // red[] reuse
    if (lane == 0) red[wid] = acc;
    __syncthreads();

    // ---- finish: partial store + mod-256 last-block election ----
    if (tid == 0) {
        float tot = 0.f;
#pragma unroll
        for (int w = 0; w < 8; ++w) tot += red[w];
        float denom = (float)npos * (float)nneg + 1e-8f;
        float scale = (npos > 0 && nneg > 0) ? 1.0f / (denom * (float)BATCH) : 0.0f;
        __hip_atomic_store(&partials[blockIdx.x], tot * scale,
                           __ATOMIC_RELEASE, __HIP_MEMORY_SCOPE_AGENT);
        unsigned int old = __hip_atomic_fetch_add(cnt, 1u, __ATOMIC_ACQ_REL,
                                                  __HIP_MEMORY_SCOPE_AGENT);
        sLast = (((old + 1u) & (NBLK - 1u)) == 0u) ? 1 : 0;
    }
    __syncthreads();
    if (sLast && wid == 0) {
        float s = 0.f;
#pragma unroll
        for (int k = 0; k < NBLK / 64; ++k)
            s += __hip_atomic_load(&partials[lane + 64 * k],
                                   __ATOMIC_ACQUIRE, __HIP_MEMORY_SCOPE_AGENT);
        for (int off = 32; off > 0; off >>= 1) s += __shfl_down(s, off);
        if (lane == 0)
            __hip_atomic_store(out, s, __ATOMIC_RELEASE, __HIP_MEMORY_SCOPE_AGENT);
    }
}

extern "C" void kernel_launch(void* const* d_in, const int* in_sizes, int n_in,
                              void* d_out, int out_size, void* d_ws, size_t ws_size,
                              hipStream_t stream) {
    const float* pred = (const float*)d_in[0];
    const float* mask = (const float*)d_in[1];
    float* out = (float*)d_out;
    float* partials = (float*)d_ws;
    unsigned int* cnt = (unsigned int*)((char*)d_ws + NBLK * sizeof(float));

    srs_fused_kernel<<<NBLK, TPB, 0, stream>>>(pred, mask, out, partials, cnt);
}

// Round 4
// 17.480 us; speedup vs baseline: 1.7103x; 1.0696x over previous
//
#include <hip/hip_runtime.h>

// Problem constants: B=8, H=64, W=64 -> N=4096 per sample
#define BATCH 8
#define N 4096
#define TPB 512
#define SPB 32                  // blocks per sample
#define NBLK (BATCH * SPB)      // 256 blocks, 1/CU, 8 waves
#define POS_F 4096              // pos region start (float index) in LDS
#define SENT_NEG -1.0e30f
#define SENT_POS  1.0e30f

// Single kernel, single graph node, 3 barriers.
//   LDS: neg list [0,4096) prefilled -1e30; pos list [4096,8192) prefilled +1e30.
//   pass 1: per-sample max (regs); pass 2: ballot-compact (1 atomic/wave/type)
//     neg -> x/max + 0.5 (front region), pos -> x/max (back region)
//   pass 3: outer over SMALLER list (always <= 2048 -> one balanced pass,
//     2 outer/thread, 16-way half-wave inner split), inner float4 over larger.
//     caseA term relu(neg_j - pos_i); caseB term relu(neg_j - pos_i) with
//     roles swapped in the loop. Sentinels make invalid slots contribute 0.
//   tail: partial -> d_ws (release), cnt mod-256 elects last block (wave 0
//     only, no barrier), winner reduces 256 partials, stores out[0].
//     cnt needs NO init: any start value works mod 256.
__global__ __launch_bounds__(TPB) void srs_fused_kernel(
    const float* __restrict__ pred,
    const float* __restrict__ mask,
    float* __restrict__ out,
    float* __restrict__ partials,       // [NBLK] floats in d_ws
    unsigned int* __restrict__ cnt)     // 1 uint in d_ws (never re-initialized)
{
    const int b    = blockIdx.x >> 5;   // / SPB
    const int c    = blockIdx.x & 31;   // % SPB
    const int tid  = threadIdx.x;
    const int lane = tid & 63;
    const int wid  = tid >> 6;          // 0..7

    __shared__ float4 comb4[2048];      // 32 KB: [0,1024) neg, [1024,2048) pos
    float* comb = (float*)comb4;
    __shared__ float red[8];
    __shared__ int ctr[2];              // [0]=npos, [1]=nneg

    const float4* xb4 = (const float4*)(pred + b * N);
    const float4* mb4 = (const float4*)(mask + b * N);

    // issue global loads first (latency overlaps prefill)
    float4 xv0 = xb4[tid];
    float4 xv1 = xb4[tid + 512];
    float4 mv0 = mb4[tid];
    float4 mv1 = mb4[tid + 512];

    // sentinel prefill + counter init
    comb4[tid]        = make_float4(SENT_NEG, SENT_NEG, SENT_NEG, SENT_NEG);
    comb4[tid + 512]  = make_float4(SENT_NEG, SENT_NEG, SENT_NEG, SENT_NEG);
    comb4[tid + 1024] = make_float4(SENT_POS, SENT_POS, SENT_POS, SENT_POS);
    comb4[tid + 1536] = make_float4(SENT_POS, SENT_POS, SENT_POS, SENT_POS);
    if (tid < 2) ctr[tid] = 0;

    // ---- pass 1: sample max ----
    float lmax = fmaxf(fmaxf(xv0.x, xv0.y), fmaxf(xv0.z, xv0.w));
    lmax = fmaxf(lmax, fmaxf(fmaxf(xv1.x, xv1.y), fmaxf(xv1.z, xv1.w)));
    for (int off = 32; off > 0; off >>= 1)
        lmax = fmaxf(lmax, __shfl_down(lmax, off));
    if (lane == 0) red[wid] = lmax;
    __syncthreads();                                    // barrier 1

    float mx = red[0];
#pragma unroll
    for (int w = 1; w < 8; ++w) mx = fmaxf(mx, red[w]);
    const float rmax = 1.0f / mx;

    // ---- pass 2: ballot compaction, 1 LDS atomic per wave per type ----
    float xs[8] = {xv0.x, xv0.y, xv0.z, xv0.w, xv1.x, xv1.y, xv1.z, xv1.w};
    float ms[8] = {mv0.x, mv0.y, mv0.z, mv0.w, mv1.x, mv1.y, mv1.z, mv1.w};
    bool isp[8], isn[8];
    unsigned long long bp[8], bn[8];
#pragma unroll
    for (int k = 0; k < 8; ++k) {
        isp[k] = ms[k] > 0.5f;
        isn[k] = ms[k] < 0.5f;
        bp[k] = __ballot(isp[k]);
        bn[k] = __ballot(isn[k]);
    }
    int cp = 0, cn = 0;
#pragma unroll
    for (int k = 0; k < 8; ++k) { cp += (int)__popcll(bp[k]); cn += (int)__popcll(bn[k]); }
    int basep = 0, basen = 0;
    if (lane == 0) {
        basep = atomicAdd(&ctr[0], cp);
        basen = atomicAdd(&ctr[1], cn);
    }
    basep = __shfl(basep, 0);
    basen = __shfl(basen, 0);
    const unsigned long long lower = (1ull << lane) - 1ull;
    int op = 0, on = 0;
#pragma unroll
    for (int k = 0; k < 8; ++k) {
        float nv = xs[k] * rmax;
        if (isp[k]) comb[POS_F + basep + op + (int)__popcll(bp[k] & lower)] = nv;
        if (isn[k]) comb[basen + on + (int)__popcll(bn[k] & lower)] = nv + 0.5f;
        op += (int)__popcll(bp[k]);
        on += (int)__popcll(bn[k]);
    }
    __syncthreads();                                    // barrier 2

    // ---- pass 3: pair loop, outer over smaller list (one balanced pass) ----
    const int npos = ctr[0], nneg = ctr[1];
    const int ii = tid & 31;            // outer lane slot (R=2: ii and ii+32)
    const int jsplit = tid >> 5;        // 0..15, half-wave inner split
    float a0=0.f,a1=0.f,a2=0.f,a3=0.f,a4=0.f,a5=0.f,a6=0.f,a7=0.f;

    if (npos <= nneg) {
        // outer = pos (smaller), inner = neg. term = relu(vneg - xi)
        const float xiA = comb[POS_F + c * 64 + ii];
        const float xiB = comb[POS_F + c * 64 + ii + 32];
        const int nj4 = (nneg + 3) >> 2;
#pragma unroll 2
        for (int j4 = jsplit; j4 < nj4; j4 += 16) {
            float4 v = comb4[j4];
            a0 += fmaxf(v.x - xiA, 0.f); a1 += fmaxf(v.y - xiA, 0.f);
            a2 += fmaxf(v.z - xiA, 0.f); a3 += fmaxf(v.w - xiA, 0.f);
            a4 += fmaxf(v.x - xiB, 0.f); a5 += fmaxf(v.y - xiB, 0.f);
            a6 += fmaxf(v.z - xiB, 0.f); a7 += fmaxf(v.w - xiB, 0.f);
        }
    } else {
        // outer = neg (smaller), inner = pos. term = relu(wj - vpos)
        const float wjA = comb[c * 64 + ii];
        const float wjB = comb[c * 64 + ii + 32];
        const int nj4 = (npos + 3) >> 2;
#pragma unroll 2
        for (int j4 = jsplit; j4 < nj4; j4 += 16) {
            float4 v = comb4[1024 + j4];
            a0 += fmaxf(wjA - v.x, 0.f); a1 += fmaxf(wjA - v.y, 0.f);
            a2 += fmaxf(wjA - v.z, 0.f); a3 += fmaxf(wjA - v.w, 0.f);
            a4 += fmaxf(wjB - v.x, 0.f); a5 += fmaxf(wjB - v.y, 0.f);
            a6 += fmaxf(wjB - v.z, 0.f); a7 += fmaxf(wjB - v.w, 0.f);
        }
    }
    float acc = ((a0 + a1) + (a2 + a3)) + ((a4 + a5) + (a6 + a7));
    for (int off = 32; off > 0; off >>= 1) acc += __shfl_down(acc, off);
    if (lane == 0) red[wid] = acc;
    __syncthreads();                                    // barrier 3

    // ---- tail: wave 0 only, no further barriers ----
    if (wid == 0) {
        float tot = 0.f;
#pragma unroll
        for (int w = 0; w < 8; ++w) tot += red[w];
        const float denom = (float)npos * (float)nneg + 1e-8f;
        const float scale = (npos > 0 && nneg > 0) ? 1.0f / (denom * (float)BATCH) : 0.0f;
        const float part = tot * scale;
        int last = 0;
        if (lane == 0) {
            __hip_atomic_store(&partials[blockIdx.x], part,
                               __ATOMIC_RELEASE, __HIP_MEMORY_SCOPE_AGENT);
            unsigned int old = __hip_atomic_fetch_add(cnt, 1u, __ATOMIC_ACQ_REL,
                                                      __HIP_MEMORY_SCOPE_AGENT);
            last = (((old + 1u) & (NBLK - 1u)) == 0u) ? 1 : 0;
        }
        last = __shfl(last, 0);
        if (last) {
            float s = 0.f;
#pragma unroll
            for (int k = 0; k < NBLK / 64; ++k)
                s += __hip_atomic_load(&partials[lane + 64 * k],
                                       __ATOMIC_RELAXED, __HIP_MEMORY_SCOPE_AGENT);
            for (int off = 32; off > 0; off >>= 1) s += __shfl_down(s, off);
            if (lane == 0)
                __hip_atomic_store(out, s, __ATOMIC_RELEASE, __HIP_MEMORY_SCOPE_AGENT);
        }
    }
}

extern "C" void kernel_launch(void* const* d_in, const int* in_sizes, int n_in,
                              void* d_out, int out_size, void* d_ws, size_t ws_size,
                              hipStream_t stream) {
    const float* pred = (const float*)d_in[0];
    const float* mask = (const float*)d_in[1];
    float* out = (float*)d_out;
    float* partials = (float*)d_ws;
    unsigned int* cnt = (unsigned int*)((char*)d_ws + NBLK * sizeof(float));

    srs_fused_kernel<<<NBLK, TPB, 0, stream>>>(pred, mask, out, partials, cnt);
}

// Round 5
// 17.084 us; speedup vs baseline: 1.7499x; 1.0231x over previous
//
#include <hip/hip_runtime.h>

// Problem constants: B=8, H=64, W=64 -> N=4096 per sample
#define BATCH 8
#define N 4096
#define TPB 512
#define SPB 32                  // blocks per sample
#define NBLK (BATCH * SPB)      // 256 blocks, 1/CU, 8 waves
#define POS_F 4096              // pos region start (float index) in LDS
#define SENT_NEG -1.0e30f
#define SENT_POS  1.0e30f

// Single kernel, single graph node, 3 barriers, no LDS atomics.
// Math: relu(0.5 - (xi - xj)/mx) == rmax * relu(0.5*mx - xi + xj)  (mx > 0),
// so compaction stores RAW values (independent of max), bias = 0.5*mx is
// applied to the outer operand, and rmax scales the per-block partial once.
//   LDS: neg raw [0,4096) prefilled -1e30; pos raw [4096,8192) prefilled +1e30.
//   pass 1: ballots + per-wave counts + wave max -> LDS slots ... barrier 1
//   pass 2: prefix-sum bases (broadcast reads), scatter raw vals ... barrier 2
//   pass 3: outer over SMALLER list (<=2048 -> one balanced pass, 4 outer per
//     thread, 32-way inner split: 1 ds_read_b128 feeds 48 VALU), barrier 3
//   tail: partial*rmax*scale -> d_ws (release), cnt mod-256 elects last block
//     (wave 0 only), winner reduces 256 partials, stores out[0].
//     cnt needs NO init: any start value works mod 256.
__global__ __launch_bounds__(TPB) void srs_fused_kernel(
    const float* __restrict__ pred,
    const float* __restrict__ mask,
    float* __restrict__ out,
    float* __restrict__ partials,       // [NBLK] floats in d_ws
    unsigned int* __restrict__ cnt)     // 1 uint in d_ws (never re-initialized)
{
    const int b    = blockIdx.x >> 5;   // / SPB
    const int c    = blockIdx.x & 31;   // % SPB
    const int tid  = threadIdx.x;
    const int lane = tid & 63;
    const int wid  = tid >> 6;          // 0..7

    __shared__ float4 comb4[2048];      // 32 KB: [0,1024) neg, [1024,2048) pos
    float* comb = (float*)comb4;
    __shared__ float red[8];            // wave maxes
    __shared__ int wcp[8], wcn[8];      // per-wave pos/neg counts

    const float4* xb4 = (const float4*)(pred + b * N);
    const float4* mb4 = (const float4*)(mask + b * N);

    // issue global loads first (latency overlaps prefill)
    float4 xv0 = xb4[tid];
    float4 xv1 = xb4[tid + 512];
    float4 mv0 = mb4[tid];
    float4 mv1 = mb4[tid + 512];

    // sentinel prefill
    comb4[tid]        = make_float4(SENT_NEG, SENT_NEG, SENT_NEG, SENT_NEG);
    comb4[tid + 512]  = make_float4(SENT_NEG, SENT_NEG, SENT_NEG, SENT_NEG);
    comb4[tid + 1024] = make_float4(SENT_POS, SENT_POS, SENT_POS, SENT_POS);
    comb4[tid + 1536] = make_float4(SENT_POS, SENT_POS, SENT_POS, SENT_POS);

    // ---- pass 1: ballots + per-wave counts + wave max ----
    float xs[8] = {xv0.x, xv0.y, xv0.z, xv0.w, xv1.x, xv1.y, xv1.z, xv1.w};
    float ms[8] = {mv0.x, mv0.y, mv0.z, mv0.w, mv1.x, mv1.y, mv1.z, mv1.w};
    bool isp[8], isn[8];
    unsigned long long bp[8], bn[8];
#pragma unroll
    for (int k = 0; k < 8; ++k) {
        isp[k] = ms[k] > 0.5f;
        isn[k] = ms[k] < 0.5f;
        bp[k] = __ballot(isp[k]);
        bn[k] = __ballot(isn[k]);
    }
    int cp = 0, cn = 0;
#pragma unroll
    for (int k = 0; k < 8; ++k) { cp += (int)__popcll(bp[k]); cn += (int)__popcll(bn[k]); }

    float lmax = fmaxf(fmaxf(xs[0], xs[1]), fmaxf(xs[2], xs[3]));
    lmax = fmaxf(lmax, fmaxf(fmaxf(xs[4], xs[5]), fmaxf(xs[6], xs[7])));
    for (int off = 32; off > 0; off >>= 1)
        lmax = fmaxf(lmax, __shfl_down(lmax, off));
    if (lane == 0) { red[wid] = lmax; wcp[wid] = cp; wcn[wid] = cn; }
    __syncthreads();                                    // barrier 1

    // ---- pass 2: prefix bases (broadcast reads) + scatter raw values ----
    float mx = red[0];
    int basep = 0, basen = 0;
#pragma unroll
    for (int w = 1; w < 8; ++w) mx = fmaxf(mx, red[w]);
#pragma unroll
    for (int w = 0; w < 8; ++w) {
        if (w < wid) { basep += wcp[w]; basen += wcn[w]; }
    }
    const float rmax = 1.0f / mx;
    const float bias = 0.5f * mx;

    const unsigned long long lower = (1ull << lane) - 1ull;
#pragma unroll
    for (int k = 0; k < 8; ++k) {
        if (isp[k]) comb[POS_F + basep + (int)__popcll(bp[k] & lower)] = xs[k];
        if (isn[k]) comb[basen + (int)__popcll(bn[k] & lower)] = xs[k];
        basep += (int)__popcll(bp[k]);
        basen += (int)__popcll(bn[k]);
    }
    __syncthreads();                                    // barrier 2

    // total counts
    int npos = 0, nneg = 0;
#pragma unroll
    for (int w = 0; w < 8; ++w) { npos += wcp[w]; nneg += wcn[w]; }

    // ---- pass 3: pair loop, outer over smaller list, R=4, 32-way split ----
    const int ii = tid & 15;            // outer slots: c*64 + ii + {0,16,32,48}
    const int jsplit = tid >> 4;        // 0..31 inner split
    float a[16];
#pragma unroll
    for (int q = 0; q < 16; ++q) a[q] = 0.f;

    if (npos <= nneg) {
        // outer = pos, inner = neg raw. term = relu(vneg - (pos - bias))
        const int obase = POS_F + c * 64 + ii;
        float xi0 = comb[obase]      - bias;
        float xi1 = comb[obase + 16] - bias;
        float xi2 = comb[obase + 32] - bias;
        float xi3 = comb[obase + 48] - bias;
        const int nj4 = (nneg + 3) >> 2;
#pragma unroll 2
        for (int j4 = jsplit; j4 < nj4; j4 += 32) {
            float4 v = comb4[j4];
            a[0]  += fmaxf(v.x - xi0, 0.f); a[1]  += fmaxf(v.y - xi0, 0.f);
            a[2]  += fmaxf(v.z - xi0, 0.f); a[3]  += fmaxf(v.w - xi0, 0.f);
            a[4]  += fmaxf(v.x - xi1, 0.f); a[5]  += fmaxf(v.y - xi1, 0.f);
            a[6]  += fmaxf(v.z - xi1, 0.f); a[7]  += fmaxf(v.w - xi1, 0.f);
            a[8]  += fmaxf(v.x - xi2, 0.f); a[9]  += fmaxf(v.y - xi2, 0.f);
            a[10] += fmaxf(v.z - xi2, 0.f); a[11] += fmaxf(v.w - xi2, 0.f);
            a[12] += fmaxf(v.x - xi3, 0.f); a[13] += fmaxf(v.y - xi3, 0.f);
            a[14] += fmaxf(v.z - xi3, 0.f); a[15] += fmaxf(v.w - xi3, 0.f);
        }
    } else {
        // outer = neg, inner = pos raw. term = relu((neg + bias) - vpos)
        const int obase = c * 64 + ii;
        float wj0 = comb[obase]      + bias;
        float wj1 = comb[obase + 16] + bias;
        float wj2 = comb[obase + 32] + bias;
        float wj3 = comb[obase + 48] + bias;
        const int nj4 = (npos + 3) >> 2;
#pragma unroll 2
        for (int j4 = jsplit; j4 < nj4; j4 += 32) {
            float4 v = comb4[1024 + j4];
            a[0]  += fmaxf(wj0 - v.x, 0.f); a[1]  += fmaxf(wj0 - v.y, 0.f);
            a[2]  += fmaxf(wj0 - v.z, 0.f); a[3]  += fmaxf(wj0 - v.w, 0.f);
            a[4]  += fmaxf(wj1 - v.x, 0.f); a[5]  += fmaxf(wj1 - v.y, 0.f);
            a[6]  += fmaxf(wj1 - v.z, 0.f); a[7]  += fmaxf(wj1 - v.w, 0.f);
            a[8]  += fmaxf(wj2 - v.x, 0.f); a[9]  += fmaxf(wj2 - v.y, 0.f);
            a[10] += fmaxf(wj2 - v.z, 0.f); a[11] += fmaxf(wj2 - v.w, 0.f);
            a[12] += fmaxf(wj3 - v.x, 0.f); a[13] += fmaxf(wj3 - v.y, 0.f);
            a[14] += fmaxf(wj3 - v.z, 0.f); a[15] += fmaxf(wj3 - v.w, 0.f);
        }
    }
    float acc = 0.f;
#pragma unroll
    for (int q = 0; q < 16; ++q) acc += a[q];
    for (int off = 32; off > 0; off >>= 1) acc += __shfl_down(acc, off);
    if (lane == 0) red[wid] = acc;
    __syncthreads();                                    // barrier 3

    // ---- tail: wave 0 only, no further barriers ----
    if (wid == 0) {
        float tot = 0.f;
#pragma unroll
        for (int w = 0; w < 8; ++w) tot += red[w];
        const float denom = (float)npos * (float)nneg + 1e-8f;
        const float scale = (npos > 0 && nneg > 0)
                          ? rmax / (denom * (float)BATCH) : 0.0f;
        const float part = tot * scale;
        int last = 0;
        if (lane == 0) {
            __hip_atomic_store(&partials[blockIdx.x], part,
                               __ATOMIC_RELEASE, __HIP_MEMORY_SCOPE_AGENT);
            unsigned int old = __hip_atomic_fetch_add(cnt, 1u, __ATOMIC_ACQ_REL,
                                                      __HIP_MEMORY_SCOPE_AGENT);
            last = (((old + 1u) & (NBLK - 1u)) == 0u) ? 1 : 0;
        }
        last = __shfl(last, 0);
        if (last) {
            float s = 0.f;
#pragma unroll
            for (int k = 0; k < NBLK / 64; ++k)
                s += __hip_atomic_load(&partials[lane + 64 * k],
                                       __ATOMIC_RELAXED, __HIP_MEMORY_SCOPE_AGENT);
            for (int off = 32; off > 0; off >>= 1) s += __shfl_down(s, off);
            if (lane == 0)
                __hip_atomic_store(out, s, __ATOMIC_RELEASE, __HIP_MEMORY_SCOPE_AGENT);
        }
    }
}

extern "C" void kernel_launch(void* const* d_in, const int* in_sizes, int n_in,
                              void* d_out, int out_size, void* d_ws, size_t ws_size,
                              hipStream_t stream) {
    const float* pred = (const float*)d_in[0];
    const float* mask = (const float*)d_in[1];
    float* out = (float*)d_out;
    float* partials = (float*)d_ws;
    unsigned int* cnt = (unsigned int*)((char*)d_ws + NBLK * sizeof(float));

    srs_fused_kernel<<<NBLK, TPB, 0, stream>>>(pred, mask, out, partials, cnt);
}